// Round 1
// baseline (430.678 us; speedup 1.0000x reference)
//
#include <hip/hip_runtime.h>

#define B_ 16
#define N_ 16384
#define C_ 128
#define H_ 512
#define W_ 512
#define L_ 65
#define FG 64

#define CHUNKS 16
#define PTS_PER_BLOCK (N_ / CHUNKS)      // 1024
#define PTS_PER_WAVE  (PTS_PER_BLOCK/4)  // 256

// ws layout (float units)
#define OFF_SUMS 0
#define OFF_CNT  (B_*L_*C_)              // 133120
#define OFF_DIST (OFF_CNT + B_*L_)       // 134160
#define OFF_LAB  (OFF_DIST + B_*L_)      // 135200 (ints from here, B_*N_)

__global__ __launch_bounds__(256) void k_zero(float* __restrict__ ws, float* __restrict__ out) {
    int i = blockIdx.x * 256 + threadIdx.x;
    if (i < OFF_LAB) ws[i] = 0.f;
    if (i == 0) out[0] = 0.f;
}

__global__ __launch_bounds__(256) void k_accum(const float* __restrict__ emb,
                                               const int2* __restrict__ coords,
                                               const int* __restrict__ y,
                                               float* __restrict__ ws) {
    __shared__ float s_sum[L_ * C_];
    __shared__ float s_cnt[L_];
    const int b = blockIdx.x / CHUNKS;
    const int chunk = blockIdx.x % CHUNKS;
    const int wave = threadIdx.x >> 6, lane = threadIdx.x & 63;

    for (int i = threadIdx.x; i < L_ * C_; i += 256) s_sum[i] = 0.f;
    if (threadIdx.x < L_) s_cnt[threadIdx.x] = 0.f;
    __syncthreads();

    int* labws = (int*)(ws + OFF_LAB);
    const float* embb = emb + (size_t)b * N_ * C_;

    for (int g = 0; g < PTS_PER_WAVE / 64; ++g) {
        const int nbase = chunk * PTS_PER_BLOCK + wave * PTS_PER_WAVE + g * 64;
        const int n = nbase + lane;
        int2 rc = coords[b * N_ + n];
        int labv = y[(b * H_ + rc.x) * W_ + rc.y];
        labws[b * N_ + n] = labv;                       // coalesced save for pass 2
        const float* ep = embb + (size_t)nbase * C_ + lane;
        for (int u0 = 0; u0 < 64; u0 += 8) {
            float e0[8], e1[8]; int lb[8];
            #pragma unroll
            for (int u = 0; u < 8; ++u) {
                lb[u] = __shfl(labv, u0 + u);
                e0[u] = ep[(u0 + u) * C_];
                e1[u] = ep[(u0 + u) * C_ + 64];
            }
            #pragma unroll
            for (int u = 0; u < 8; ++u) {
                atomicAdd(&s_sum[lb[u] * C_ + lane],      e0[u]);
                atomicAdd(&s_sum[lb[u] * C_ + 64 + lane], e1[u]);
                if (lane == 0) atomicAdd(&s_cnt[lb[u]], 1.f);
            }
        }
    }
    __syncthreads();
    float* gs = ws + OFF_SUMS + b * L_ * C_;
    for (int i = threadIdx.x; i < L_ * C_; i += 256) atomicAdd(&gs[i], s_sum[i]);
    float* gc = ws + OFF_CNT + b * L_;
    if (threadIdx.x < L_) atomicAdd(&gc[threadIdx.x], s_cnt[threadIdx.x]);
}

__global__ __launch_bounds__(256) void k_final_cent(float* __restrict__ ws) {
    int i = blockIdx.x * 256 + threadIdx.x;
    if (i >= B_ * L_ * C_) return;
    float cnt = ws[OFF_CNT + (i / C_)];
    ws[OFF_SUMS + i] = ws[OFF_SUMS + i] / fmaxf(cnt, 1.f);
}

__global__ __launch_bounds__(256) void k_dist(const float* __restrict__ emb,
                                              float* __restrict__ ws) {
    __shared__ float s_cent[L_ * C_];
    __shared__ float s_dist[L_];
    const int b = blockIdx.x / CHUNKS;
    const int chunk = blockIdx.x % CHUNKS;
    const int wave = threadIdx.x >> 6, lane = threadIdx.x & 63;

    const float* gcent = ws + OFF_SUMS + b * L_ * C_;
    for (int i = threadIdx.x; i < L_ * C_; i += 256) s_cent[i] = gcent[i];
    if (threadIdx.x < L_) s_dist[threadIdx.x] = 0.f;
    __syncthreads();

    const int* labws = (const int*)(ws + OFF_LAB) + b * N_;
    const float* embb = emb + (size_t)b * N_ * C_;

    for (int g = 0; g < PTS_PER_WAVE / 64; ++g) {
        const int nbase = chunk * PTS_PER_BLOCK + wave * PTS_PER_WAVE + g * 64;
        int labv = labws[nbase + lane];
        const float* ep = embb + (size_t)nbase * C_ + lane;
        for (int u0 = 0; u0 < 64; u0 += 8) {
            float e0[8], e1[8]; int lb[8];
            #pragma unroll
            for (int u = 0; u < 8; ++u) {
                lb[u] = __shfl(labv, u0 + u);
                e0[u] = ep[(u0 + u) * C_];
                e1[u] = ep[(u0 + u) * C_ + 64];
            }
            #pragma unroll
            for (int u = 0; u < 8; ++u) {
                float d0 = e0[u] - s_cent[lb[u] * C_ + lane];
                float d1 = e1[u] - s_cent[lb[u] * C_ + 64 + lane];
                float ss = d0 * d0 + d1 * d1;
                #pragma unroll
                for (int off = 32; off; off >>= 1) ss += __shfl_xor(ss, off);
                if (lane == 0) atomicAdd(&s_dist[lb[u]], sqrtf(fmaxf(ss, 1e-12f)));
            }
        }
    }
    __syncthreads();
    float* gd = ws + OFF_DIST + b * L_;
    if (threadIdx.x < L_) atomicAdd(&gd[threadIdx.x], s_dist[threadIdx.x]);
}

#define CSTRIDE 132  // 128 + 4 pad -> conflict-free float4 tile reads

__global__ __launch_bounds__(256) void k_final(float* __restrict__ ws, float* __restrict__ out) {
    __shared__ __align__(16) float s_cc[FG * CSTRIDE];
    __shared__ float s_present[FG];
    __shared__ float s_red[3];  // [0]=pull, [1]=push num, [2]=npairs
    const int b = blockIdx.x;
    const int t = threadIdx.x;

    const float* gcent = ws + OFF_SUMS + b * L_ * C_;
    for (int i = t; i < FG * C_; i += 256) {
        int l = i >> 7, ch = i & 127;
        s_cc[l * CSTRIDE + ch] = gcent[(l + 1) * C_ + ch];
    }
    if (t < 3) s_red[t] = 0.f;
    if (t < FG) {  // exactly wave 0
        float cnt = ws[OFF_CNT + b * L_ + 1 + t];
        s_present[t] = (cnt > 0.f) ? 1.f : 0.f;
        float pl = (cnt > 0.f) ? ws[OFF_DIST + b * L_ + 1 + t] / cnt : 0.f;
        #pragma unroll
        for (int off = 32; off; off >>= 1) pl += __shfl_xor(pl, off);
        if (t == 0) s_red[0] = pl;
    }
    __syncthreads();

    const int wave = t >> 6, lane = t & 63;
    const int ti = lane >> 3, tj = lane & 7;
    float psum = 0.f, pnp = 0.f;
    for (int tt = wave; tt < 36; tt += 4) {
        int a = 0, c = tt;
        while (c >= 8 - a) { c -= 8 - a; ++a; }
        c += a;  // tile (a, c), a <= c
        int i = a * 8 + ti, j = c * 8 + tj;
        float acc = 0.f;
        #pragma unroll
        for (int ch = 0; ch < C_; ch += 4) {
            float4 xi = *(const float4*)&s_cc[i * CSTRIDE + ch];
            float4 xj = *(const float4*)&s_cc[j * CSTRIDE + ch];
            float dx = xi.x - xj.x, dy = xi.y - xj.y;
            float dz = xi.z - xj.z, dw = xi.w - xj.w;
            acc += dx * dx + dy * dy + dz * dz + dw * dw;
        }
        float dm = sqrtf(fmaxf(acc, 1e-12f));
        float pv = fmaxf(1.f - dm, 0.f);           // PUSH_MARGIN = 1
        bool valid = (i < j) && (s_present[i] > 0.f) && (s_present[j] > 0.f);
        if (valid) { psum += pv; pnp += 1.f; }
    }
    #pragma unroll
    for (int off = 32; off; off >>= 1) {
        psum += __shfl_xor(psum, off);
        pnp  += __shfl_xor(pnp,  off);
    }
    if (lane == 0) { atomicAdd(&s_red[1], psum); atomicAdd(&s_red[2], pnp); }
    __syncthreads();
    if (t == 0) {
        float loss = s_red[0] + s_red[1] / fmaxf(s_red[2], 1.f);
        atomicAdd(out, loss);
    }
}

extern "C" void kernel_launch(void* const* d_in, const int* in_sizes, int n_in,
                              void* d_out, int out_size, void* d_ws, size_t ws_size,
                              hipStream_t stream) {
    const float* emb   = (const float*)d_in[0];
    const int2* coords = (const int2*)d_in[1];
    const int*  y      = (const int*)d_in[2];
    float* out = (float*)d_out;
    float* ws  = (float*)d_ws;

    k_zero<<<(OFF_LAB + 255) / 256, 256, 0, stream>>>(ws, out);
    k_accum<<<B_ * CHUNKS, 256, 0, stream>>>(emb, coords, y, ws);
    k_final_cent<<<(B_ * L_ * C_ + 255) / 256, 256, 0, stream>>>(ws);
    k_dist<<<B_ * CHUNKS, 256, 0, stream>>>(emb, ws);
    k_final<<<B_, 256, 0, stream>>>(ws, out);
}

// Round 2
// 372.418 us; speedup vs baseline: 1.1564x; 1.1564x over previous
//
#include <hip/hip_runtime.h>

#define B_ 16
#define N_ 16384
#define C_ 128
#define H_ 512
#define W_ 512
#define L_ 65
#define FG 64

#define CHUNKS 16
#define PTS_PER_BLOCK (N_ / CHUNKS)      // 1024
#define BLK 1024                          // 16 waves/block, 1 block/CU

// ws layout (float units)
#define OFF_SUMS 0
#define OFF_CNT  (B_*L_*C_)              // 133120
#define OFF_DIST (OFF_CNT + B_*L_)       // 134160
#define OFF_LAB  (OFF_DIST + B_*L_)      // 135200 (ints from here, B_*N_)

__global__ __launch_bounds__(256) void k_zero(float* __restrict__ ws, float* __restrict__ out) {
    int i = blockIdx.x * 256 + threadIdx.x;
    if (i < OFF_LAB) ws[i] = 0.f;
    if (i == 0) out[0] = 0.f;
}

__global__ __launch_bounds__(BLK) void k_accum(const float* __restrict__ emb,
                                               const int2* __restrict__ coords,
                                               const int* __restrict__ y,
                                               float* __restrict__ ws) {
    __shared__ float s_sum[L_ * C_];
    __shared__ float s_cnt[L_];
    const int b = blockIdx.x / CHUNKS;
    const int chunk = blockIdx.x % CHUNKS;
    const int wave = threadIdx.x >> 6, lane = threadIdx.x & 63;

    for (int i = threadIdx.x; i < L_ * C_; i += BLK) s_sum[i] = 0.f;
    if (threadIdx.x < L_) s_cnt[threadIdx.x] = 0.f;
    __syncthreads();

    int* labws = (int*)(ws + OFF_LAB);
    const float* embb = emb + (size_t)b * N_ * C_;

    // each wave owns exactly 64 points
    const int nbase = chunk * PTS_PER_BLOCK + wave * 64;
    const int n = nbase + lane;
    int2 rc = coords[b * N_ + n];
    int labv = y[(b * H_ + rc.x) * W_ + rc.y];
    labws[b * N_ + n] = labv;                       // coalesced save for pass 2
    atomicAdd(&s_cnt[labv], 1.f);                   // one count per point
    const float* ep = embb + (size_t)nbase * C_ + lane;
    for (int u0 = 0; u0 < 64; u0 += 8) {
        float e0[8], e1[8]; int lb[8];
        #pragma unroll
        for (int u = 0; u < 8; ++u) {
            lb[u] = __shfl(labv, u0 + u);
            e0[u] = ep[(u0 + u) * C_];
            e1[u] = ep[(u0 + u) * C_ + 64];
        }
        #pragma unroll
        for (int u = 0; u < 8; ++u) {
            atomicAdd(&s_sum[lb[u] * C_ + lane],      e0[u]);
            atomicAdd(&s_sum[lb[u] * C_ + 64 + lane], e1[u]);
        }
    }
    __syncthreads();
    float* gs = ws + OFF_SUMS + b * L_ * C_;
    for (int i = threadIdx.x; i < L_ * C_; i += BLK) atomicAdd(&gs[i], s_sum[i]);
    float* gc = ws + OFF_CNT + b * L_;
    if (threadIdx.x < L_) atomicAdd(&gc[threadIdx.x], s_cnt[threadIdx.x]);
}

__global__ __launch_bounds__(256) void k_final_cent(float* __restrict__ ws) {
    int i = blockIdx.x * 256 + threadIdx.x;
    if (i >= B_ * L_ * C_) return;
    float cnt = ws[OFF_CNT + (i / C_)];
    ws[OFF_SUMS + i] = ws[OFF_SUMS + i] / fmaxf(cnt, 1.f);
}

__global__ __launch_bounds__(BLK) void k_dist(const float* __restrict__ emb,
                                              float* __restrict__ ws) {
    __shared__ float s_cent[L_ * C_];
    __shared__ float s_dist[L_];
    const int b = blockIdx.x / CHUNKS;
    const int chunk = blockIdx.x % CHUNKS;
    const int wave = threadIdx.x >> 6, lane = threadIdx.x & 63;

    const float* gcent = ws + OFF_SUMS + b * L_ * C_;
    for (int i = threadIdx.x; i < L_ * C_; i += BLK) s_cent[i] = gcent[i];
    if (threadIdx.x < L_) s_dist[threadIdx.x] = 0.f;
    __syncthreads();

    const int* labws = (const int*)(ws + OFF_LAB) + b * N_;
    const float* embb = emb + (size_t)b * N_ * C_;

    const int nbase = chunk * PTS_PER_BLOCK + wave * 64;
    int labv = labws[nbase + lane];
    const float* ep = embb + (size_t)nbase * C_ + lane;
    for (int u0 = 0; u0 < 64; u0 += 8) {
        float e0[8], e1[8]; int lb[8];
        #pragma unroll
        for (int u = 0; u < 8; ++u) {
            lb[u] = __shfl(labv, u0 + u);
            e0[u] = ep[(u0 + u) * C_];
            e1[u] = ep[(u0 + u) * C_ + 64];
        }
        float ss[8];
        #pragma unroll
        for (int u = 0; u < 8; ++u) {
            float d0 = e0[u] - s_cent[lb[u] * C_ + lane];
            float d1 = e1[u] - s_cent[lb[u] * C_ + 64 + lane];
            ss[u] = d0 * d0 + d1 * d1;
        }
        // merge-tree reduction: 8 per-point partials x 64 lanes -> lane&7 holds point u0+(lane&7)
        float m[4];
        #pragma unroll
        for (int k = 0; k < 4; ++k) {
            float x = ss[2 * k], yv = ss[2 * k + 1];
            float keep = (lane & 1) ? yv : x;
            float send = (lane & 1) ? x : yv;
            m[k] = keep + __shfl_xor(send, 1);
        }
        float narr[2];
        #pragma unroll
        for (int k = 0; k < 2; ++k) {
            float x = m[2 * k], yv = m[2 * k + 1];
            float keep = (lane & 2) ? yv : x;
            float send = (lane & 2) ? x : yv;
            narr[k] = keep + __shfl_xor(send, 2);
        }
        float r;
        {
            float x = narr[0], yv = narr[1];
            float keep = (lane & 4) ? yv : x;
            float send = (lane & 4) ? x : yv;
            r = keep + __shfl_xor(send, 4);
        }
        r += __shfl_xor(r, 8);
        r += __shfl_xor(r, 16);
        r += __shfl_xor(r, 32);
        float d = sqrtf(fmaxf(r, 1e-12f));
        int mylab = __shfl(labv, u0 + (lane & 7));
        if (lane < 8) atomicAdd(&s_dist[mylab], d);
    }
    __syncthreads();
    float* gd = ws + OFF_DIST + b * L_;
    if (threadIdx.x < L_) atomicAdd(&gd[threadIdx.x], s_dist[threadIdx.x]);
}

#define CSTRIDE 132  // 128 + 4 pad -> conflict-free float4 tile reads

__global__ __launch_bounds__(256) void k_final(float* __restrict__ ws, float* __restrict__ out) {
    __shared__ __align__(16) float s_cc[FG * CSTRIDE];
    __shared__ float s_present[FG];
    __shared__ float s_red[3];  // [0]=pull, [1]=push num, [2]=npairs
    const int b = blockIdx.x;
    const int t = threadIdx.x;

    const float* gcent = ws + OFF_SUMS + b * L_ * C_;
    for (int i = t; i < FG * C_; i += 256) {
        int l = i >> 7, ch = i & 127;
        s_cc[l * CSTRIDE + ch] = gcent[(l + 1) * C_ + ch];
    }
    if (t < 3) s_red[t] = 0.f;
    if (t < FG) {  // exactly wave 0
        float cnt = ws[OFF_CNT + b * L_ + 1 + t];
        s_present[t] = (cnt > 0.f) ? 1.f : 0.f;
        float pl = (cnt > 0.f) ? ws[OFF_DIST + b * L_ + 1 + t] / cnt : 0.f;
        #pragma unroll
        for (int off = 32; off; off >>= 1) pl += __shfl_xor(pl, off);
        if (t == 0) s_red[0] = pl;
    }
    __syncthreads();

    const int wave = t >> 6, lane = t & 63;
    const int ti = lane >> 3, tj = lane & 7;
    float psum = 0.f, pnp = 0.f;
    for (int tt = wave; tt < 36; tt += 4) {
        int a = 0, c = tt;
        while (c >= 8 - a) { c -= 8 - a; ++a; }
        c += a;  // tile (a, c), a <= c
        int i = a * 8 + ti, j = c * 8 + tj;
        float acc = 0.f;
        #pragma unroll
        for (int ch = 0; ch < C_; ch += 4) {
            float4 xi = *(const float4*)&s_cc[i * CSTRIDE + ch];
            float4 xj = *(const float4*)&s_cc[j * CSTRIDE + ch];
            float dx = xi.x - xj.x, dy = xi.y - xj.y;
            float dz = xi.z - xj.z, dw = xi.w - xj.w;
            acc += dx * dx + dy * dy + dz * dz + dw * dw;
        }
        float dm = sqrtf(fmaxf(acc, 1e-12f));
        float pv = fmaxf(1.f - dm, 0.f);           // PUSH_MARGIN = 1
        bool valid = (i < j) && (s_present[i] > 0.f) && (s_present[j] > 0.f);
        if (valid) { psum += pv; pnp += 1.f; }
    }
    #pragma unroll
    for (int off = 32; off; off >>= 1) {
        psum += __shfl_xor(psum, off);
        pnp  += __shfl_xor(pnp,  off);
    }
    if (lane == 0) { atomicAdd(&s_red[1], psum); atomicAdd(&s_red[2], pnp); }
    __syncthreads();
    if (t == 0) {
        float loss = s_red[0] + s_red[1] / fmaxf(s_red[2], 1.f);
        atomicAdd(out, loss);
    }
}

extern "C" void kernel_launch(void* const* d_in, const int* in_sizes, int n_in,
                              void* d_out, int out_size, void* d_ws, size_t ws_size,
                              hipStream_t stream) {
    const float* emb   = (const float*)d_in[0];
    const int2* coords = (const int2*)d_in[1];
    const int*  y      = (const int*)d_in[2];
    float* out = (float*)d_out;
    float* ws  = (float*)d_ws;

    k_zero<<<(OFF_LAB + 255) / 256, 256, 0, stream>>>(ws, out);
    k_accum<<<B_ * CHUNKS, BLK, 0, stream>>>(emb, coords, y, ws);
    k_final_cent<<<(B_ * L_ * C_ + 255) / 256, 256, 0, stream>>>(ws);
    k_dist<<<B_ * CHUNKS, BLK, 0, stream>>>(emb, ws);
    k_final<<<B_, 256, 0, stream>>>(ws, out);
}

// Round 3
// 371.235 us; speedup vs baseline: 1.1601x; 1.0032x over previous
//
#include <hip/hip_runtime.h>

#define B_ 16
#define N_ 16384
#define C_ 128
#define H_ 512
#define W_ 512
#define L_ 65
#define FG 64

#define CHUNKS 16
#define PTS_PER_BLOCK (N_ / CHUNKS)      // 1024
#define BLK 1024                          // 16 waves/block, 1 block/CU

// ws layout (float units)
#define OFF_SUMS 0
#define OFF_CNT  (B_*L_*C_)              // 133120
#define OFF_DIST (OFF_CNT + B_*L_)       // 134160
#define OFF_LAB  (OFF_DIST + B_*L_)      // 135200 (ints from here, B_*N_)

__global__ __launch_bounds__(256) void k_zero(float* __restrict__ ws, float* __restrict__ out) {
    int i = blockIdx.x * 256 + threadIdx.x;
    if (i < OFF_LAB) ws[i] = 0.f;
    if (i == 0) out[0] = 0.f;
}

__global__ __launch_bounds__(BLK) void k_accum(const float* __restrict__ emb,
                                               const int2* __restrict__ coords,
                                               const int* __restrict__ y,
                                               float* __restrict__ ws) {
    __shared__ float s_sum[L_ * C_];
    __shared__ float s_cnt[L_];
    const int b = blockIdx.x / CHUNKS;
    const int chunk = blockIdx.x % CHUNKS;
    const int wave = threadIdx.x >> 6, lane = threadIdx.x & 63;

    for (int i = threadIdx.x; i < L_ * C_; i += BLK) s_sum[i] = 0.f;
    if (threadIdx.x < L_) s_cnt[threadIdx.x] = 0.f;
    __syncthreads();

    int* labws = (int*)(ws + OFF_LAB);
    const float* embb = emb + (size_t)b * N_ * C_;

    // each wave owns exactly 64 points
    const int nbase = chunk * PTS_PER_BLOCK + wave * 64;
    const int n = nbase + lane;
    int2 rc = coords[b * N_ + n];
    int labv = y[(b * H_ + rc.x) * W_ + rc.y];
    labws[b * N_ + n] = labv;                       // coalesced save for pass 2
    unsafeAtomicAdd(&s_cnt[labv], 1.f);             // native ds_add_f32
    const float* ep = embb + (size_t)nbase * C_ + lane;
    for (int u0 = 0; u0 < 64; u0 += 8) {
        float e0[8], e1[8]; int lb[8];
        #pragma unroll
        for (int u = 0; u < 8; ++u) {
            lb[u] = __shfl(labv, u0 + u);
            e0[u] = ep[(u0 + u) * C_];
            e1[u] = ep[(u0 + u) * C_ + 64];
        }
        #pragma unroll
        for (int u = 0; u < 8; ++u) {
            unsafeAtomicAdd(&s_sum[lb[u] * C_ + lane],      e0[u]);
            unsafeAtomicAdd(&s_sum[lb[u] * C_ + 64 + lane], e1[u]);
        }
    }
    __syncthreads();
    float* gs = ws + OFF_SUMS + b * L_ * C_;
    for (int i = threadIdx.x; i < L_ * C_; i += BLK) unsafeAtomicAdd(&gs[i], s_sum[i]);
    float* gc = ws + OFF_CNT + b * L_;
    if (threadIdx.x < L_) unsafeAtomicAdd(&gc[threadIdx.x], s_cnt[threadIdx.x]);
}

__global__ __launch_bounds__(256) void k_final_cent(float* __restrict__ ws) {
    int i = blockIdx.x * 256 + threadIdx.x;
    if (i >= B_ * L_ * C_) return;
    float cnt = ws[OFF_CNT + (i / C_)];
    ws[OFF_SUMS + i] = ws[OFF_SUMS + i] / fmaxf(cnt, 1.f);
}

__global__ __launch_bounds__(BLK) void k_dist(const float* __restrict__ emb,
                                              float* __restrict__ ws) {
    __shared__ float s_cent[L_ * C_];
    __shared__ float s_dist[L_];
    const int b = blockIdx.x / CHUNKS;
    const int chunk = blockIdx.x % CHUNKS;
    const int wave = threadIdx.x >> 6, lane = threadIdx.x & 63;

    const float* gcent = ws + OFF_SUMS + b * L_ * C_;
    for (int i = threadIdx.x; i < L_ * C_; i += BLK) s_cent[i] = gcent[i];
    if (threadIdx.x < L_) s_dist[threadIdx.x] = 0.f;
    __syncthreads();

    const int* labws = (const int*)(ws + OFF_LAB) + b * N_;
    const float* embb = emb + (size_t)b * N_ * C_;

    const int nbase = chunk * PTS_PER_BLOCK + wave * 64;
    int labv = labws[nbase + lane];
    const float* ep = embb + (size_t)nbase * C_ + lane;
    for (int u0 = 0; u0 < 64; u0 += 8) {
        float e0[8], e1[8]; int lb[8];
        #pragma unroll
        for (int u = 0; u < 8; ++u) {
            lb[u] = __shfl(labv, u0 + u);
            e0[u] = ep[(u0 + u) * C_];
            e1[u] = ep[(u0 + u) * C_ + 64];
        }
        float ss[8];
        #pragma unroll
        for (int u = 0; u < 8; ++u) {
            float d0 = e0[u] - s_cent[lb[u] * C_ + lane];
            float d1 = e1[u] - s_cent[lb[u] * C_ + 64 + lane];
            ss[u] = d0 * d0 + d1 * d1;
        }
        // merge-tree reduction: 8 per-point partials x 64 lanes -> lane&7 holds point u0+(lane&7)
        float m[4];
        #pragma unroll
        for (int k = 0; k < 4; ++k) {
            float x = ss[2 * k], yv = ss[2 * k + 1];
            float keep = (lane & 1) ? yv : x;
            float send = (lane & 1) ? x : yv;
            m[k] = keep + __shfl_xor(send, 1);
        }
        float narr[2];
        #pragma unroll
        for (int k = 0; k < 2; ++k) {
            float x = m[2 * k], yv = m[2 * k + 1];
            float keep = (lane & 2) ? yv : x;
            float send = (lane & 2) ? x : yv;
            narr[k] = keep + __shfl_xor(send, 2);
        }
        float r;
        {
            float x = narr[0], yv = narr[1];
            float keep = (lane & 4) ? yv : x;
            float send = (lane & 4) ? x : yv;
            r = keep + __shfl_xor(send, 4);
        }
        r += __shfl_xor(r, 8);
        r += __shfl_xor(r, 16);
        r += __shfl_xor(r, 32);
        float d = sqrtf(fmaxf(r, 1e-12f));
        int mylab = __shfl(labv, u0 + (lane & 7));
        if (lane < 8) unsafeAtomicAdd(&s_dist[mylab], d);
    }
    __syncthreads();
    float* gd = ws + OFF_DIST + b * L_;
    if (threadIdx.x < L_) unsafeAtomicAdd(&gd[threadIdx.x], s_dist[threadIdx.x]);
}

#define CSTRIDE 132  // 128 + 4 pad -> conflict-free float4 tile reads

__global__ __launch_bounds__(256) void k_final(float* __restrict__ ws, float* __restrict__ out) {
    __shared__ __align__(16) float s_cc[FG * CSTRIDE];
    __shared__ float s_present[FG];
    __shared__ float s_red[3];  // [0]=pull, [1]=push num, [2]=npairs
    const int b = blockIdx.x;
    const int t = threadIdx.x;

    const float* gcent = ws + OFF_SUMS + b * L_ * C_;
    for (int i = t; i < FG * C_; i += 256) {
        int l = i >> 7, ch = i & 127;
        s_cc[l * CSTRIDE + ch] = gcent[(l + 1) * C_ + ch];
    }
    if (t < 3) s_red[t] = 0.f;
    if (t < FG) {  // exactly wave 0
        float cnt = ws[OFF_CNT + b * L_ + 1 + t];
        s_present[t] = (cnt > 0.f) ? 1.f : 0.f;
        float pl = (cnt > 0.f) ? ws[OFF_DIST + b * L_ + 1 + t] / cnt : 0.f;
        #pragma unroll
        for (int off = 32; off; off >>= 1) pl += __shfl_xor(pl, off);
        if (t == 0) s_red[0] = pl;
    }
    __syncthreads();

    const int wave = t >> 6, lane = t & 63;
    const int ti = lane >> 3, tj = lane & 7;
    float psum = 0.f, pnp = 0.f;
    for (int tt = wave; tt < 36; tt += 4) {
        int a = 0, c = tt;
        while (c >= 8 - a) { c -= 8 - a; ++a; }
        c += a;  // tile (a, c), a <= c
        int i = a * 8 + ti, j = c * 8 + tj;
        float acc = 0.f;
        #pragma unroll
        for (int ch = 0; ch < C_; ch += 4) {
            float4 xi = *(const float4*)&s_cc[i * CSTRIDE + ch];
            float4 xj = *(const float4*)&s_cc[j * CSTRIDE + ch];
            float dx = xi.x - xj.x, dy = xi.y - xj.y;
            float dz = xi.z - xj.z, dw = xi.w - xj.w;
            acc += dx * dx + dy * dy + dz * dz + dw * dw;
        }
        float dm = sqrtf(fmaxf(acc, 1e-12f));
        float pv = fmaxf(1.f - dm, 0.f);           // PUSH_MARGIN = 1
        bool valid = (i < j) && (s_present[i] > 0.f) && (s_present[j] > 0.f);
        if (valid) { psum += pv; pnp += 1.f; }
    }
    #pragma unroll
    for (int off = 32; off; off >>= 1) {
        psum += __shfl_xor(psum, off);
        pnp  += __shfl_xor(pnp,  off);
    }
    if (lane == 0) { unsafeAtomicAdd(&s_red[1], psum); unsafeAtomicAdd(&s_red[2], pnp); }
    __syncthreads();
    if (t == 0) {
        float loss = s_red[0] + s_red[1] / fmaxf(s_red[2], 1.f);
        unsafeAtomicAdd(out, loss);
    }
}

extern "C" void kernel_launch(void* const* d_in, const int* in_sizes, int n_in,
                              void* d_out, int out_size, void* d_ws, size_t ws_size,
                              hipStream_t stream) {
    const float* emb   = (const float*)d_in[0];
    const int2* coords = (const int2*)d_in[1];
    const int*  y      = (const int*)d_in[2];
    float* out = (float*)d_out;
    float* ws  = (float*)d_ws;

    k_zero<<<(OFF_LAB + 255) / 256, 256, 0, stream>>>(ws, out);
    k_accum<<<B_ * CHUNKS, BLK, 0, stream>>>(emb, coords, y, ws);
    k_final_cent<<<(B_ * L_ * C_ + 255) / 256, 256, 0, stream>>>(ws);
    k_dist<<<B_ * CHUNKS, BLK, 0, stream>>>(emb, ws);
    k_final<<<B_, 256, 0, stream>>>(ws, out);
}